// Round 1
// baseline (10234.523 us; speedup 1.0000x reference)
//
#include <hip/hip_runtime.h>
#include <math.h>

#define NNODES 50000
#define NEDGES 600000
#define HIDDIM 128
#define NHEAD 8
#define DA 16
#define DV 16
#define DM 64
#define NCLS 40

static __device__ __forceinline__ unsigned int fkey(float f) {
    unsigned int b = __float_as_uint(f);
    return (b & 0x80000000u) ? ~b : (b | 0x80000000u);
}
static __device__ __forceinline__ float fdecode(unsigned int k) {
    if (k == 0u) return 0.0f;  // empty segment sentinel -> 0 (matches reference)
    unsigned int b = (k & 0x80000000u) ? (k & 0x7FFFFFFFu) : ~k;
    return __uint_as_float(b);
}

// ---------------- GEMM: C[M,NN] = act( [A1|A2][M,K1+K2] @ B[K1+K2,NN] ) ----
// 64x64 block tile, 256 threads, 4x4 micro-tile, LDS-staged chunks of K=16.
template <int ACT>
__global__ __launch_bounds__(256) void gemm_dual(
    const float* __restrict__ A1, int K1,
    const float* __restrict__ A2, int K2,
    const float* __restrict__ B,
    float* __restrict__ C, int M, int NN)
{
    const int K = K1 + K2;
    __shared__ float As[16][68];   // transposed: As[k][row], +4 pad keeps 16B align
    __shared__ float Bs[16][64];

    const int t  = threadIdx.x;
    const int tx = t & 15, ty = t >> 4;
    const int row0 = blockIdx.y * 64, col0 = blockIdx.x * 64;

    float acc[4][4];
#pragma unroll
    for (int i = 0; i < 4; ++i)
#pragma unroll
        for (int j = 0; j < 4; ++j) acc[i][j] = 0.f;

    const int ar  = (t * 4) >> 4;   // 0..63  (A row within tile)
    const int akc = (t * 4) & 15;   // 0,4,8,12 (A k within chunk)
    const int bkc = (t * 4) >> 6;   // 0..15  (B k within chunk)
    const int bc  = (t * 4) & 63;   // B col within tile (multiple of 4)

    for (int k0 = 0; k0 < K; k0 += 16) {
        // stage A chunk (64 rows x 16 k), transposed into As
        {
            int row = row0 + ar;
            float4 f = make_float4(0.f, 0.f, 0.f, 0.f);
            if (row < M) {
                int kg = k0 + akc;  // multiple of 4; K1 multiple of 4 -> no straddle
                if (kg < K1)
                    f = *reinterpret_cast<const float4*>(A1 + (size_t)row * K1 + kg);
                else
                    f = *reinterpret_cast<const float4*>(A2 + (size_t)row * K2 + (kg - K1));
            }
            As[akc + 0][ar] = f.x;
            As[akc + 1][ar] = f.y;
            As[akc + 2][ar] = f.z;
            As[akc + 3][ar] = f.w;
        }
        // stage B chunk (16 k x 64 cols)
        {
            int kg = k0 + bkc;
            const float* brow = B + (size_t)kg * NN;
            float4 bf;
            int c0 = col0 + bc;
            if (c0 + 4 <= NN) {
                bf = *reinterpret_cast<const float4*>(brow + c0);
            } else {
                bf.x = (c0 + 0 < NN) ? brow[c0 + 0] : 0.f;
                bf.y = (c0 + 1 < NN) ? brow[c0 + 1] : 0.f;
                bf.z = (c0 + 2 < NN) ? brow[c0 + 2] : 0.f;
                bf.w = (c0 + 3 < NN) ? brow[c0 + 3] : 0.f;
            }
            *reinterpret_cast<float4*>(&Bs[bkc][bc]) = bf;
        }
        __syncthreads();
#pragma unroll
        for (int kk = 0; kk < 16; ++kk) {
            float4 a = *reinterpret_cast<const float4*>(&As[kk][ty * 4]);
            float4 b = *reinterpret_cast<const float4*>(&Bs[kk][tx * 4]);
            float av[4] = {a.x, a.y, a.z, a.w};
            float bv[4] = {b.x, b.y, b.z, b.w};
#pragma unroll
            for (int i = 0; i < 4; ++i)
#pragma unroll
                for (int j = 0; j < 4; ++j)
                    acc[i][j] = fmaf(av[i], bv[j], acc[i][j]);
        }
        __syncthreads();
    }
#pragma unroll
    for (int i = 0; i < 4; ++i) {
        int row = row0 + ty * 4 + i;
        if (row >= M) continue;
#pragma unroll
        for (int j = 0; j < 4; ++j) {
            int col = col0 + tx * 4 + j;
            if (col >= NN) continue;
            float vv = acc[i][j];
            if (ACT == 1) vv = vv > 0.f ? vv : 0.1f * vv;
            C[(size_t)row * NN + col] = vv;
        }
    }
}

// ---------------- edge kernels -------------------------------------------
__global__ __launch_bounds__(256) void edge_score_kernel(
    const int* __restrict__ ei, const float* __restrict__ q,
    const float* __restrict__ kmat, float* __restrict__ escore,
    unsigned int* __restrict__ smax_i)
{
    int idx = blockIdx.x * 256 + threadIdx.x;
    if (idx >= NEDGES * NHEAD) return;
    int e = idx >> 3, hd = idx & 7;
    unsigned s = (unsigned)ei[e];          if (s >= NNODES) s = 0;
    unsigned d = (unsigned)ei[NEDGES + e]; if (d >= NNODES) d = 0;
    const float4* qp = reinterpret_cast<const float4*>(q + (size_t)d * HIDDIM + hd * DA);
    const float4* kp = reinterpret_cast<const float4*>(kmat + (size_t)s * HIDDIM + hd * DA);
    float acc = 0.f;
#pragma unroll
    for (int j = 0; j < 4; ++j) {
        float4 a = qp[j], b = kp[j];
        acc += a.x * b.x + a.y * b.y + a.z * b.z + a.w * b.w;
    }
    escore[idx] = acc;
    atomicMax(smax_i + (size_t)d * NHEAD + hd, fkey(acc));
}

__global__ __launch_bounds__(256) void edge_exp_kernel(
    const int* __restrict__ ei, float* __restrict__ escore,
    const unsigned int* __restrict__ smax_i, float* __restrict__ denom)
{
    int idx = blockIdx.x * 256 + threadIdx.x;
    if (idx >= NEDGES * NHEAD) return;
    int e = idx >> 3, hd = idx & 7;
    unsigned d = (unsigned)ei[NEDGES + e]; if (d >= NNODES) d = 0;
    float mx = fdecode(smax_i[(size_t)d * NHEAD + hd]);
    float ex = __expf(escore[idx] - mx);
    escore[idx] = ex;
    atomicAdd(denom + (size_t)d * NHEAD + hd, ex);
}

__global__ __launch_bounds__(256) void edge_agg_kernel(
    const int* __restrict__ ei, const float* __restrict__ escore,
    const float* __restrict__ denom, const float* __restrict__ v,
    float* __restrict__ agg)
{
    int idx = blockIdx.x * 256 + threadIdx.x;
    if (idx >= NEDGES * NHEAD) return;
    int e = idx >> 3, hd = idx & 7;
    unsigned s = (unsigned)ei[e];          if (s >= NNODES) s = 0;
    unsigned d = (unsigned)ei[NEDGES + e]; if (d >= NNODES) d = 0;
    float alpha = escore[idx] / (denom[(size_t)d * NHEAD + hd] + 1e-16f);
    const float4* vp = reinterpret_cast<const float4*>(v + (size_t)s * HIDDIM + hd * DV);
    float* ap = agg + (size_t)d * HIDDIM + hd * DV;
#pragma unroll
    for (int j = 0; j < 4; ++j) {
        float4 vv = vp[j];
        atomicAdd(ap + 4 * j + 0, alpha * vv.x);
        atomicAdd(ap + 4 * j + 1, alpha * vv.y);
        atomicAdd(ap + 4 * j + 2, alpha * vv.z);
        atomicAdd(ap + 4 * j + 3, alpha * vv.w);
    }
}

__global__ __launch_bounds__(256) void edge_pool_kernel(
    const int* __restrict__ ei, const float* __restrict__ h,
    const float* __restrict__ m, float* __restrict__ meansum,
    unsigned int* __restrict__ maxpool_i, float* __restrict__ deg)
{
    int idx = blockIdx.x * 256 + threadIdx.x;
    if (idx >= NEDGES * HIDDIM) return;
    int e = idx >> 7, dcol = idx & 127;
    unsigned s = (unsigned)ei[e];          if (s >= NNODES) s = 0;
    unsigned d = (unsigned)ei[NEDGES + e]; if (d >= NNODES) d = 0;
    atomicAdd(meansum + (size_t)d * HIDDIM + dcol, h[(size_t)s * HIDDIM + dcol]);
    if (dcol < DM)
        atomicMax(maxpool_i + (size_t)d * DM + dcol, fkey(m[(size_t)s * DM + dcol]));
    if (dcol == 0) atomicAdd(deg + d, 1.0f);
}

// ---------------- gate / gated / log-softmax ------------------------------
__global__ __launch_bounds__(256) void gate_kernel(
    const float* __restrict__ h, const unsigned int* __restrict__ maxpool_i,
    const float* __restrict__ meansum, const float* __restrict__ deg,
    const float* __restrict__ Wg, float* __restrict__ g8)
{
    int idx = blockIdx.x * 256 + threadIdx.x;
    if (idx >= NNODES * NHEAD) return;
    int n = idx >> 3, j = idx & 7;
    const float* hr = h + (size_t)n * HIDDIM;
    float sacc = 0.f;
    for (int c = 0; c < HIDDIM; ++c) sacc += hr[c] * Wg[c * NHEAD + j];
    const unsigned int* mp = maxpool_i + (size_t)n * DM;
    for (int c = 0; c < DM; ++c) sacc += fdecode(mp[c]) * Wg[(HIDDIM + c) * NHEAD + j];
    float invd = 1.0f / fmaxf(deg[n], 1.0f);
    const float* ms = meansum + (size_t)n * HIDDIM;
    for (int c = 0; c < HIDDIM; ++c) sacc += ms[c] * invd * Wg[(HIDDIM + DM + c) * NHEAD + j];
    g8[idx] = 1.0f / (1.0f + __expf(-sacc));
}

__global__ __launch_bounds__(256) void gated_kernel(
    const float* __restrict__ g8, const float* __restrict__ agg,
    float* __restrict__ gated)
{
    int idx = blockIdx.x * 256 + threadIdx.x;
    if (idx >= NNODES * HIDDIM) return;
    int n = idx >> 7, c = idx & 127;
    gated[idx] = g8[n * NHEAD + (c >> 4)] * agg[idx];
}

__global__ __launch_bounds__(256) void logsoftmax_kernel(float* __restrict__ out)
{
    int gt = blockIdx.x * 256 + threadIdx.x;
    int wid = gt >> 6;
    int lane = threadIdx.x & 63;
    if (wid >= NNODES) return;
    float* row = out + (size_t)wid * NCLS;
    float x = (lane < NCLS) ? row[lane] : -INFINITY;
    float mx = x;
#pragma unroll
    for (int off = 32; off; off >>= 1) mx = fmaxf(mx, __shfl_xor(mx, off));
    float ex = (lane < NCLS) ? __expf(x - mx) : 0.f;
    float sm = ex;
#pragma unroll
    for (int off = 32; off; off >>= 1) sm += __shfl_xor(sm, off);
    float lse = mx + logf(sm);
    if (lane < NCLS) row[lane] = x - lse;
}

// ---------------- host ----------------------------------------------------
static inline int cdiv(int a, int b) { return (a + b - 1) / b; }

extern "C" void kernel_launch(void* const* d_in, const int* in_sizes, int n_in,
                              void* d_out, int out_size, void* d_ws, size_t ws_size,
                              hipStream_t stream)
{
    const float* x     = (const float*)d_in[0];
    const int*   ei    = (const int*)d_in[1];
    const float* w_in  = (const float*)d_in[2];
    const float* w_out = (const float*)d_in[3];
    const float* Wq    = (const float*)d_in[4];
    const float* Wk    = (const float*)d_in[5];
    const float* Wv    = (const float*)d_in[6];
    const float* Wm    = (const float*)d_in[7];
    const float* Wg    = (const float*)d_in[8];
    const float* Wo    = (const float*)d_in[9];
    float* out = (float*)d_out;

    const size_t NF = NNODES;
    float* ws = (float*)d_ws;
    float* h      = ws;                         // N*128
    float* h2     = h  + NF * 128;              // N*128
    float* q      = h2 + NF * 128;              // N*128 (reused as 'gated')
    float* kk     = q  + NF * 128;              // N*128
    float* v      = kk + NF * 128;              // N*128
    float* m      = v  + NF * 128;              // N*64
    float* g8     = m  + NF * 64;               // N*8
    float* escore = g8 + NF * 8;                // E*8
    float* zr     = escore + (size_t)NEDGES * 8;
    unsigned int* smax_i    = (unsigned int*)zr;            // N*8
    float*        denom     = zr + NF * 8;                  // N*8
    float*        agg       = denom + NF * 8;               // N*128
    unsigned int* maxpool_i = (unsigned int*)(agg + NF * 128); // N*64
    float*        meansum   = agg + NF * 128 + NF * 64;     // N*128
    float*        deg       = meansum + NF * 128;           // N
    const size_t zr_floats = NF * (8 + 8 + 128 + 64 + 128 + 1);

    auto gemm = [&](const float* A1, int K1, const float* A2, int K2,
                    const float* B, float* C, int M, int NN, int act) {
        dim3 grid(cdiv(NN, 64), cdiv(M, 64));
        if (act)
            gemm_dual<1><<<grid, 256, 0, stream>>>(A1, K1, A2, K2, B, C, M, NN);
        else
            gemm_dual<0><<<grid, 256, 0, stream>>>(A1, K1, A2, K2, B, C, M, NN);
    };

    // h = x @ weight_in
    gemm(x, 128, nullptr, 0, w_in, h, NNODES, 128, 0);

    const float* hin = h;
    float* hout = h2;
    const int ebk = cdiv(NEDGES * NHEAD, 256);
    for (int L = 0; L < 2; ++L) {
        const float* wq = Wq + (size_t)L * 128 * 128;
        const float* wk = Wk + (size_t)L * 128 * 128;
        const float* wv = Wv + (size_t)L * 128 * 128;
        const float* wm = Wm + (size_t)L * 128 * 64;
        const float* wg = Wg + (size_t)L * 320 * 8;
        const float* wo = Wo + (size_t)L * 256 * 128;

        hipMemsetAsync(zr, 0, zr_floats * sizeof(float), stream);

        gemm(hin, 128, nullptr, 0, wq, q,  NNODES, 128, 0);
        gemm(hin, 128, nullptr, 0, wk, kk, NNODES, 128, 0);
        gemm(hin, 128, nullptr, 0, wv, v,  NNODES, 128, 0);
        gemm(hin, 128, nullptr, 0, wm, m,  NNODES, 64,  0);

        edge_score_kernel<<<ebk, 256, 0, stream>>>(ei, q, kk, escore, smax_i);
        edge_pool_kernel<<<cdiv(NEDGES * HIDDIM, 256), 256, 0, stream>>>(
            ei, hin, m, meansum, maxpool_i, deg);
        edge_exp_kernel<<<ebk, 256, 0, stream>>>(ei, escore, smax_i, denom);
        edge_agg_kernel<<<ebk, 256, 0, stream>>>(ei, escore, denom, v, agg);

        gate_kernel<<<cdiv(NNODES * NHEAD, 256), 256, 0, stream>>>(
            hin, maxpool_i, meansum, deg, wg, g8);
        gated_kernel<<<cdiv(NNODES * HIDDIM, 256), 256, 0, stream>>>(g8, agg, q);

        gemm(hin, 128, q, 128, wo, hout, NNODES, 128, 1);

        const float* tmp = hout;
        hout = (float*)hin;
        hin = tmp;
    }

    // classifier + log-softmax (hin holds the final hidden state)
    gemm(hin, 128, nullptr, 0, w_out, out, NNODES, NCLS, 0);
    logsoftmax_kernel<<<cdiv(NNODES * 64, 256), 256, 0, stream>>>(out);
}

// Round 2
// 2127.065 us; speedup vs baseline: 4.8116x; 4.8116x over previous
//
#include <hip/hip_runtime.h>
#include <math.h>

#define NNODES 50000
#define NEDGES 600000
#define HIDDIM 128
#define NHEAD 8
#define DA 16
#define DV 16
#define DM 64
#define NCLS 40

static __device__ __forceinline__ unsigned int fkey(float f) {
    unsigned int b = __float_as_uint(f);
    return (b & 0x80000000u) ? ~b : (b | 0x80000000u);
}
static __device__ __forceinline__ float fdecode(unsigned int k) {
    if (k == 0u) return 0.0f;  // empty segment sentinel -> 0 (matches reference)
    unsigned int b = (k & 0x80000000u) ? (k & 0x7FFFFFFFu) : ~k;
    return __uint_as_float(b);
}

// ---------------- GEMM: C[M,NN] = act( [A1|A2][M,K1+K2] @ B[K1+K2,NN] ) ----
// 64x64 block tile, 256 threads, 4x4 micro-tile, LDS-staged chunks of K=16.
template <int ACT>
__global__ __launch_bounds__(256) void gemm_dual(
    const float* __restrict__ A1, int K1,
    const float* __restrict__ A2, int K2,
    const float* __restrict__ B,
    float* __restrict__ C, int M, int NN)
{
    const int K = K1 + K2;
    __shared__ float As[16][68];   // transposed: As[k][row], +4 pad keeps 16B align
    __shared__ float Bs[16][64];

    const int t  = threadIdx.x;
    const int tx = t & 15, ty = t >> 4;
    const int row0 = blockIdx.y * 64, col0 = blockIdx.x * 64;

    float acc[4][4];
#pragma unroll
    for (int i = 0; i < 4; ++i)
#pragma unroll
        for (int j = 0; j < 4; ++j) acc[i][j] = 0.f;

    const int ar  = (t * 4) >> 4;   // 0..63  (A row within tile)
    const int akc = (t * 4) & 15;   // 0,4,8,12 (A k within chunk)
    const int bkc = (t * 4) >> 6;   // 0..15  (B k within chunk)
    const int bc  = (t * 4) & 63;   // B col within tile (multiple of 4)

    for (int k0 = 0; k0 < K; k0 += 16) {
        // stage A chunk (64 rows x 16 k), transposed into As
        {
            int row = row0 + ar;
            float4 f = make_float4(0.f, 0.f, 0.f, 0.f);
            if (row < M) {
                int kg = k0 + akc;  // multiple of 4; K1 multiple of 4 -> no straddle
                if (kg < K1)
                    f = *reinterpret_cast<const float4*>(A1 + (size_t)row * K1 + kg);
                else
                    f = *reinterpret_cast<const float4*>(A2 + (size_t)row * K2 + (kg - K1));
            }
            As[akc + 0][ar] = f.x;
            As[akc + 1][ar] = f.y;
            As[akc + 2][ar] = f.z;
            As[akc + 3][ar] = f.w;
        }
        // stage B chunk (16 k x 64 cols)
        {
            int kg = k0 + bkc;
            const float* brow = B + (size_t)kg * NN;
            float4 bf;
            int c0 = col0 + bc;
            if (c0 + 4 <= NN) {
                bf = *reinterpret_cast<const float4*>(brow + c0);
            } else {
                bf.x = (c0 + 0 < NN) ? brow[c0 + 0] : 0.f;
                bf.y = (c0 + 1 < NN) ? brow[c0 + 1] : 0.f;
                bf.z = (c0 + 2 < NN) ? brow[c0 + 2] : 0.f;
                bf.w = (c0 + 3 < NN) ? brow[c0 + 3] : 0.f;
            }
            *reinterpret_cast<float4*>(&Bs[bkc][bc]) = bf;
        }
        __syncthreads();
#pragma unroll
        for (int kk = 0; kk < 16; ++kk) {
            float4 a = *reinterpret_cast<const float4*>(&As[kk][ty * 4]);
            float4 b = *reinterpret_cast<const float4*>(&Bs[kk][tx * 4]);
            float av[4] = {a.x, a.y, a.z, a.w};
            float bv[4] = {b.x, b.y, b.z, b.w};
#pragma unroll
            for (int i = 0; i < 4; ++i)
#pragma unroll
                for (int j = 0; j < 4; ++j)
                    acc[i][j] = fmaf(av[i], bv[j], acc[i][j]);
        }
        __syncthreads();
    }
#pragma unroll
    for (int i = 0; i < 4; ++i) {
        int row = row0 + ty * 4 + i;
        if (row >= M) continue;
#pragma unroll
        for (int j = 0; j < 4; ++j) {
            int col = col0 + tx * 4 + j;
            if (col >= NN) continue;
            float vv = acc[i][j];
            if (ACT == 1) vv = vv > 0.f ? vv : 0.1f * vv;
            C[(size_t)row * NN + col] = vv;
        }
    }
}

// ---------------- edge kernels -------------------------------------------
__global__ __launch_bounds__(256) void edge_score_kernel(
    const int* __restrict__ ei, const float* __restrict__ q,
    const float* __restrict__ kmat, float* __restrict__ escore,
    unsigned int* __restrict__ smax_i)
{
    int idx = blockIdx.x * 256 + threadIdx.x;
    if (idx >= NEDGES * NHEAD) return;
    int e = idx >> 3, hd = idx & 7;
    unsigned s = (unsigned)ei[e];          if (s >= NNODES) s = 0;
    unsigned d = (unsigned)ei[NEDGES + e]; if (d >= NNODES) d = 0;
    const float4* qp = reinterpret_cast<const float4*>(q + (size_t)d * HIDDIM + hd * DA);
    const float4* kp = reinterpret_cast<const float4*>(kmat + (size_t)s * HIDDIM + hd * DA);
    float acc = 0.f;
#pragma unroll
    for (int j = 0; j < 4; ++j) {
        float4 a = qp[j], b = kp[j];
        acc += a.x * b.x + a.y * b.y + a.z * b.z + a.w * b.w;
    }
    escore[idx] = acc;
    atomicMax(smax_i + (size_t)d * NHEAD + hd, fkey(acc));
}

__global__ __launch_bounds__(256) void edge_exp_kernel(
    const int* __restrict__ ei, float* __restrict__ escore,
    const unsigned int* __restrict__ smax_i, float* __restrict__ denom)
{
    int idx = blockIdx.x * 256 + threadIdx.x;
    if (idx >= NEDGES * NHEAD) return;
    int e = idx >> 3, hd = idx & 7;
    unsigned d = (unsigned)ei[NEDGES + e]; if (d >= NNODES) d = 0;
    float mx = fdecode(smax_i[(size_t)d * NHEAD + hd]);
    float ex = __expf(escore[idx] - mx);
    escore[idx] = ex;
    atomicAdd(denom + (size_t)d * NHEAD + hd, ex);
}

// one thread per (edge, column): single coalesced atomicAdd per thread.
__global__ __launch_bounds__(256) void edge_agg_kernel(
    const int* __restrict__ ei, const float* __restrict__ escore,
    const float* __restrict__ denom, const float* __restrict__ v,
    float* __restrict__ agg)
{
    int idx = blockIdx.x * 256 + threadIdx.x;
    if (idx >= NEDGES * HIDDIM) return;
    int e = idx >> 7, c = idx & 127;
    int hd = c >> 4;
    unsigned s = (unsigned)ei[e];          if (s >= NNODES) s = 0;
    unsigned d = (unsigned)ei[NEDGES + e]; if (d >= NNODES) d = 0;
    float alpha = escore[(size_t)e * NHEAD + hd] /
                  (denom[(size_t)d * NHEAD + hd] + 1e-16f);
    atomicAdd(agg + (size_t)d * HIDDIM + c,
              alpha * v[(size_t)s * HIDDIM + c]);
}

__global__ __launch_bounds__(256) void edge_pool_kernel(
    const int* __restrict__ ei, const float* __restrict__ h,
    const float* __restrict__ m, float* __restrict__ meansum,
    unsigned int* __restrict__ maxpool_i, float* __restrict__ deg)
{
    int idx = blockIdx.x * 256 + threadIdx.x;
    if (idx >= NEDGES * HIDDIM) return;
    int e = idx >> 7, dcol = idx & 127;
    unsigned s = (unsigned)ei[e];          if (s >= NNODES) s = 0;
    unsigned d = (unsigned)ei[NEDGES + e]; if (d >= NNODES) d = 0;
    atomicAdd(meansum + (size_t)d * HIDDIM + dcol, h[(size_t)s * HIDDIM + dcol]);
    if (dcol < DM)
        atomicMax(maxpool_i + (size_t)d * DM + dcol, fkey(m[(size_t)s * DM + dcol]));
    if (dcol == 0) atomicAdd(deg + d, 1.0f);
}

// ---------------- gate / gated / log-softmax ------------------------------
__global__ __launch_bounds__(256) void gate_kernel(
    const float* __restrict__ h, const unsigned int* __restrict__ maxpool_i,
    const float* __restrict__ meansum, const float* __restrict__ deg,
    const float* __restrict__ Wg, float* __restrict__ g8)
{
    int idx = blockIdx.x * 256 + threadIdx.x;
    if (idx >= NNODES * NHEAD) return;
    int n = idx >> 3, j = idx & 7;
    const float* hr = h + (size_t)n * HIDDIM;
    float sacc = 0.f;
    for (int c = 0; c < HIDDIM; ++c) sacc += hr[c] * Wg[c * NHEAD + j];
    const unsigned int* mp = maxpool_i + (size_t)n * DM;
    for (int c = 0; c < DM; ++c) sacc += fdecode(mp[c]) * Wg[(HIDDIM + c) * NHEAD + j];
    float invd = 1.0f / fmaxf(deg[n], 1.0f);
    const float* ms = meansum + (size_t)n * HIDDIM;
    for (int c = 0; c < HIDDIM; ++c) sacc += ms[c] * invd * Wg[(HIDDIM + DM + c) * NHEAD + j];
    g8[idx] = 1.0f / (1.0f + __expf(-sacc));
}

__global__ __launch_bounds__(256) void gated_kernel(
    const float* __restrict__ g8, const float* __restrict__ agg,
    float* __restrict__ gated)
{
    int idx = blockIdx.x * 256 + threadIdx.x;
    if (idx >= NNODES * HIDDIM) return;
    int n = idx >> 7, c = idx & 127;
    gated[idx] = g8[n * NHEAD + (c >> 4)] * agg[idx];
}

__global__ __launch_bounds__(256) void logsoftmax_kernel(float* __restrict__ out)
{
    int gt = blockIdx.x * 256 + threadIdx.x;
    int wid = gt >> 6;
    int lane = threadIdx.x & 63;
    if (wid >= NNODES) return;
    float* row = out + (size_t)wid * NCLS;
    float x = (lane < NCLS) ? row[lane] : -INFINITY;
    float mx = x;
#pragma unroll
    for (int off = 32; off; off >>= 1) mx = fmaxf(mx, __shfl_xor(mx, off));
    float ex = (lane < NCLS) ? __expf(x - mx) : 0.f;
    float sm = ex;
#pragma unroll
    for (int off = 32; off; off >>= 1) sm += __shfl_xor(sm, off);
    float lse = mx + logf(sm);
    if (lane < NCLS) row[lane] = x - lse;
}

// ---------------- host ----------------------------------------------------
static inline int cdiv(int a, int b) { return (a + b - 1) / b; }

extern "C" void kernel_launch(void* const* d_in, const int* in_sizes, int n_in,
                              void* d_out, int out_size, void* d_ws, size_t ws_size,
                              hipStream_t stream)
{
    const float* x     = (const float*)d_in[0];
    const int*   ei    = (const int*)d_in[1];
    const float* w_in  = (const float*)d_in[2];
    const float* w_out = (const float*)d_in[3];
    const float* Wq    = (const float*)d_in[4];
    const float* Wk    = (const float*)d_in[5];
    const float* Wv    = (const float*)d_in[6];
    const float* Wm    = (const float*)d_in[7];
    const float* Wg    = (const float*)d_in[8];
    const float* Wo    = (const float*)d_in[9];
    float* out = (float*)d_out;

    const size_t NF = NNODES;
    float* ws = (float*)d_ws;
    float* h      = ws;                         // N*128
    float* h2     = h  + NF * 128;              // N*128
    float* q      = h2 + NF * 128;              // N*128 (reused as 'gated')
    float* kk     = q  + NF * 128;              // N*128
    float* v      = kk + NF * 128;              // N*128
    float* m      = v  + NF * 128;              // N*64
    float* g8     = m  + NF * 64;               // N*8
    float* escore = g8 + NF * 8;                // E*8
    float* zr     = escore + (size_t)NEDGES * 8;
    unsigned int* smax_i    = (unsigned int*)zr;            // N*8
    float*        denom     = zr + NF * 8;                  // N*8
    float*        agg       = denom + NF * 8;               // N*128
    unsigned int* maxpool_i = (unsigned int*)(agg + NF * 128); // N*64
    float*        meansum   = agg + NF * 128 + NF * 64;     // N*128
    float*        deg       = meansum + NF * 128;           // N
    const size_t zr_floats = NF * (8 + 8 + 128 + 64 + 128 + 1);

    auto gemm = [&](const float* A1, int K1, const float* A2, int K2,
                    const float* B, float* C, int M, int NN, int act) {
        dim3 grid(cdiv(NN, 64), cdiv(M, 64));
        if (act)
            gemm_dual<1><<<grid, 256, 0, stream>>>(A1, K1, A2, K2, B, C, M, NN);
        else
            gemm_dual<0><<<grid, 256, 0, stream>>>(A1, K1, A2, K2, B, C, M, NN);
    };

    // h = x @ weight_in
    gemm(x, 128, nullptr, 0, w_in, h, NNODES, 128, 0);

    const float* hin = h;
    float* hout = h2;
    const int ebk = cdiv(NEDGES * NHEAD, 256);
    const int ebk128 = cdiv(NEDGES * HIDDIM, 256);
    for (int L = 0; L < 2; ++L) {
        const float* wq = Wq + (size_t)L * 128 * 128;
        const float* wk = Wk + (size_t)L * 128 * 128;
        const float* wv = Wv + (size_t)L * 128 * 128;
        const float* wm = Wm + (size_t)L * 128 * 64;
        const float* wg = Wg + (size_t)L * 320 * 8;
        const float* wo = Wo + (size_t)L * 256 * 128;

        hipMemsetAsync(zr, 0, zr_floats * sizeof(float), stream);

        gemm(hin, 128, nullptr, 0, wq, q,  NNODES, 128, 0);
        gemm(hin, 128, nullptr, 0, wk, kk, NNODES, 128, 0);
        gemm(hin, 128, nullptr, 0, wv, v,  NNODES, 128, 0);
        gemm(hin, 128, nullptr, 0, wm, m,  NNODES, 64,  0);

        edge_score_kernel<<<ebk, 256, 0, stream>>>(ei, q, kk, escore, smax_i);
        edge_pool_kernel<<<ebk128, 256, 0, stream>>>(
            ei, hin, m, meansum, maxpool_i, deg);
        edge_exp_kernel<<<ebk, 256, 0, stream>>>(ei, escore, smax_i, denom);
        edge_agg_kernel<<<ebk128, 256, 0, stream>>>(ei, escore, denom, v, agg);

        gate_kernel<<<cdiv(NNODES * NHEAD, 256), 256, 0, stream>>>(
            hin, maxpool_i, meansum, deg, wg, g8);
        gated_kernel<<<cdiv(NNODES * HIDDIM, 256), 256, 0, stream>>>(g8, agg, q);

        gemm(hin, 128, q, 128, wo, hout, NNODES, 128, 1);

        const float* tmp = hout;
        hout = (float*)hin;
        hin = tmp;
    }

    // classifier + log-softmax (hin holds the final hidden state)
    gemm(hin, 128, nullptr, 0, w_out, out, NNODES, NCLS, 0);
    logsoftmax_kernel<<<cdiv(NNODES * 64, 256), 256, 0, stream>>>(out);
}

// Round 3
// 1036.936 us; speedup vs baseline: 9.8700x; 2.0513x over previous
//
#include <hip/hip_runtime.h>
#include <math.h>

#define NNODES 50000
#define NEDGES 600000
#define HIDDIM 128
#define NHEAD 8
#define DA 16
#define DV 16
#define DM 64
#define NCLS 40

// ---------------- GEMM: C[M,NN] = act( [A1|A2][M,K1+K2] @ B[K1+K2,NN] ) ----
// 64x64 block tile, 256 threads, 4x4 micro-tile, LDS-staged chunks of K=16.
template <int ACT>
__global__ __launch_bounds__(256) void gemm_dual(
    const float* __restrict__ A1, int K1,
    const float* __restrict__ A2, int K2,
    const float* __restrict__ B,
    float* __restrict__ C, int M, int NN)
{
    const int K = K1 + K2;
    __shared__ float As[16][68];
    __shared__ float Bs[16][64];

    const int t  = threadIdx.x;
    const int tx = t & 15, ty = t >> 4;
    const int row0 = blockIdx.y * 64, col0 = blockIdx.x * 64;

    float acc[4][4];
#pragma unroll
    for (int i = 0; i < 4; ++i)
#pragma unroll
        for (int j = 0; j < 4; ++j) acc[i][j] = 0.f;

    const int ar  = (t * 4) >> 4;
    const int akc = (t * 4) & 15;
    const int bkc = (t * 4) >> 6;
    const int bc  = (t * 4) & 63;

    for (int k0 = 0; k0 < K; k0 += 16) {
        {
            int row = row0 + ar;
            float4 f = make_float4(0.f, 0.f, 0.f, 0.f);
            if (row < M) {
                int kg = k0 + akc;
                if (kg < K1)
                    f = *reinterpret_cast<const float4*>(A1 + (size_t)row * K1 + kg);
                else
                    f = *reinterpret_cast<const float4*>(A2 + (size_t)row * K2 + (kg - K1));
            }
            As[akc + 0][ar] = f.x;
            As[akc + 1][ar] = f.y;
            As[akc + 2][ar] = f.z;
            As[akc + 3][ar] = f.w;
        }
        {
            int kg = k0 + bkc;
            const float* brow = B + (size_t)kg * NN;
            float4 bf;
            int c0 = col0 + bc;
            if (c0 + 4 <= NN) {
                bf = *reinterpret_cast<const float4*>(brow + c0);
            } else {
                bf.x = (c0 + 0 < NN) ? brow[c0 + 0] : 0.f;
                bf.y = (c0 + 1 < NN) ? brow[c0 + 1] : 0.f;
                bf.z = (c0 + 2 < NN) ? brow[c0 + 2] : 0.f;
                bf.w = (c0 + 3 < NN) ? brow[c0 + 3] : 0.f;
            }
            *reinterpret_cast<float4*>(&Bs[bkc][bc]) = bf;
        }
        __syncthreads();
#pragma unroll
        for (int kk = 0; kk < 16; ++kk) {
            float4 a = *reinterpret_cast<const float4*>(&As[kk][ty * 4]);
            float4 b = *reinterpret_cast<const float4*>(&Bs[kk][tx * 4]);
            float av[4] = {a.x, a.y, a.z, a.w};
            float bv[4] = {b.x, b.y, b.z, b.w};
#pragma unroll
            for (int i = 0; i < 4; ++i)
#pragma unroll
                for (int j = 0; j < 4; ++j)
                    acc[i][j] = fmaf(av[i], bv[j], acc[i][j]);
        }
        __syncthreads();
    }
#pragma unroll
    for (int i = 0; i < 4; ++i) {
        int row = row0 + ty * 4 + i;
        if (row >= M) continue;
#pragma unroll
        for (int j = 0; j < 4; ++j) {
            int col = col0 + tx * 4 + j;
            if (col >= NN) continue;
            float vv = acc[i][j];
            if (ACT == 1) vv = vv > 0.f ? vv : 0.1f * vv;
            C[(size_t)row * NN + col] = vv;
        }
    }
}

// ---------------- CSR build ------------------------------------------------
__global__ __launch_bounds__(256) void hist_kernel(
    const int* __restrict__ ei, int* __restrict__ degi)
{
    int e = blockIdx.x * 256 + threadIdx.x;
    if (e >= NEDGES) return;
    unsigned d = (unsigned)ei[NEDGES + e]; if (d >= NNODES) d = 0;
    atomicAdd(&degi[d], 1);
}

__global__ __launch_bounds__(1024) void scan_kernel(
    const int* __restrict__ degi, int* __restrict__ rowptr)
{
    __shared__ int sh[1024];
    const int t = threadIdx.x;
    const int chunk = (NNODES + 1023) / 1024;   // 49
    int lo = t * chunk, hi = min(lo + chunk, NNODES);
    int s = 0;
    for (int i = lo; i < hi; ++i) s += degi[i];
    sh[t] = s;
    __syncthreads();
    for (int off = 1; off < 1024; off <<= 1) {
        int v = (t >= off) ? sh[t - off] : 0;
        __syncthreads();
        sh[t] += v;
        __syncthreads();
    }
    int excl = (t == 0) ? 0 : sh[t - 1];
    for (int i = lo; i < hi; ++i) {
        rowptr[i] = excl;
        excl += degi[i];
    }
    if (t == 1023) rowptr[NNODES] = excl;
}

__global__ __launch_bounds__(256) void scatter_kernel(
    const int* __restrict__ ei, const int* __restrict__ rowptr,
    int* __restrict__ fill, int* __restrict__ csr_src)
{
    int e = blockIdx.x * 256 + threadIdx.x;
    if (e >= NEDGES) return;
    unsigned s = (unsigned)ei[e];          if (s >= NNODES) s = 0;
    unsigned d = (unsigned)ei[NEDGES + e]; if (d >= NNODES) d = 0;
    int pos = rowptr[d] + atomicAdd(&fill[d], 1);
    csr_src[pos] = (int)s;
}

// ---------------- fused per-node edge phase (online softmax) --------------
// one wave per dst node; lane l owns cols 2l,2l+1 (head = l/8).
__global__ __launch_bounds__(256) void fused_edge_kernel(
    const int* __restrict__ rowptr, const int* __restrict__ csr_src,
    const float* __restrict__ q, const float* __restrict__ kmat,
    const float* __restrict__ v, const float* __restrict__ hfeat,
    const float* __restrict__ m,
    float* __restrict__ agg, float* __restrict__ meanpool,
    float* __restrict__ maxpool)
{
    int node = blockIdx.x * 4 + (threadIdx.x >> 6);
    if (node >= NNODES) return;
    const int lane = threadIdx.x & 63;
    const int c2 = lane * 2;

    const int start = rowptr[node], end = rowptr[node + 1];
    const int deg = end - start;

    float2 qv = *reinterpret_cast<const float2*>(q + (size_t)node * HIDDIM + c2);

    float mr = -INFINITY;          // running max (per 8-lane head group)
    float dr = 0.f;                // running denom
    float a0 = 0.f, a1 = 0.f;      // running weighted v accum
    float ms0 = 0.f, ms1 = 0.f;    // mean-pool sums
    float mm = -INFINITY;          // max-pool (col = lane, DM=64)

    for (int p = start; p < end; ++p) {
        int s = csr_src[p];
        float2 kv = *reinterpret_cast<const float2*>(kmat + (size_t)s * HIDDIM + c2);
        float2 vv = *reinterpret_cast<const float2*>(v    + (size_t)s * HIDDIM + c2);
        float2 hv = *reinterpret_cast<const float2*>(hfeat + (size_t)s * HIDDIM + c2);
        float  mv = m[(size_t)s * DM + lane];

        float sc = qv.x * kv.x + qv.y * kv.y;
        sc += __shfl_xor(sc, 1);
        sc += __shfl_xor(sc, 2);
        sc += __shfl_xor(sc, 4);   // all 8 lanes of the head group hold the score

        if (sc > mr) {
            float scale = __expf(mr - sc);
            dr *= scale; a0 *= scale; a1 *= scale;
            mr = sc;
        }
        float ex = __expf(sc - mr);
        dr += ex;
        a0 = fmaf(ex, vv.x, a0);
        a1 = fmaf(ex, vv.y, a1);

        ms0 += hv.x; ms1 += hv.y;
        mm = fmaxf(mm, mv);
    }

    float inv  = 1.f / (dr + 1e-16f);
    float invd = 1.f / fmaxf((float)deg, 1.f);
    if (deg == 0) { mm = 0.f; a0 = 0.f; a1 = 0.f; inv = 0.f; }

    float* ag = agg + (size_t)node * HIDDIM + c2;
    ag[0] = a0 * inv; ag[1] = a1 * inv;
    float* mp = meanpool + (size_t)node * HIDDIM + c2;
    mp[0] = ms0 * invd; mp[1] = ms1 * invd;
    maxpool[(size_t)node * DM + lane] = mm;
}

// ---------------- gate / gated / log-softmax ------------------------------
__global__ __launch_bounds__(256) void gate_kernel(
    const float* __restrict__ h, const float* __restrict__ maxpool,
    const float* __restrict__ meanpool, const float* __restrict__ Wg,
    float* __restrict__ g8)
{
    int idx = blockIdx.x * 256 + threadIdx.x;
    if (idx >= NNODES * NHEAD) return;
    int n = idx >> 3, j = idx & 7;
    const float* hr = h + (size_t)n * HIDDIM;
    float sacc = 0.f;
    for (int c = 0; c < HIDDIM; ++c) sacc += hr[c] * Wg[c * NHEAD + j];
    const float* mp = maxpool + (size_t)n * DM;
    for (int c = 0; c < DM; ++c) sacc += mp[c] * Wg[(HIDDIM + c) * NHEAD + j];
    const float* ms = meanpool + (size_t)n * HIDDIM;
    for (int c = 0; c < HIDDIM; ++c) sacc += ms[c] * Wg[(HIDDIM + DM + c) * NHEAD + j];
    g8[idx] = 1.0f / (1.0f + __expf(-sacc));
}

__global__ __launch_bounds__(256) void gated_kernel(
    const float* __restrict__ g8, const float* __restrict__ agg,
    float* __restrict__ gated)
{
    int idx = blockIdx.x * 256 + threadIdx.x;
    if (idx >= NNODES * HIDDIM) return;
    int n = idx >> 7, c = idx & 127;
    gated[idx] = g8[n * NHEAD + (c >> 4)] * agg[idx];
}

__global__ __launch_bounds__(256) void logsoftmax_kernel(float* __restrict__ out)
{
    int gt = blockIdx.x * 256 + threadIdx.x;
    int wid = gt >> 6;
    int lane = threadIdx.x & 63;
    if (wid >= NNODES) return;
    float* row = out + (size_t)wid * NCLS;
    float x = (lane < NCLS) ? row[lane] : -INFINITY;
    float mx = x;
#pragma unroll
    for (int off = 32; off; off >>= 1) mx = fmaxf(mx, __shfl_xor(mx, off));
    float ex = (lane < NCLS) ? __expf(x - mx) : 0.f;
    float sm = ex;
#pragma unroll
    for (int off = 32; off; off >>= 1) sm += __shfl_xor(sm, off);
    float lse = mx + logf(sm);
    if (lane < NCLS) row[lane] = x - lse;
}

// ---------------- host ----------------------------------------------------
static inline int cdiv(int a, int b) { return (a + b - 1) / b; }

extern "C" void kernel_launch(void* const* d_in, const int* in_sizes, int n_in,
                              void* d_out, int out_size, void* d_ws, size_t ws_size,
                              hipStream_t stream)
{
    const float* x     = (const float*)d_in[0];
    const int*   ei    = (const int*)d_in[1];
    const float* w_in  = (const float*)d_in[2];
    const float* w_out = (const float*)d_in[3];
    const float* Wq    = (const float*)d_in[4];
    const float* Wk    = (const float*)d_in[5];
    const float* Wv    = (const float*)d_in[6];
    const float* Wm    = (const float*)d_in[7];
    const float* Wg    = (const float*)d_in[8];
    const float* Wo    = (const float*)d_in[9];
    float* out = (float*)d_out;

    const size_t NF = NNODES;
    float* ws = (float*)d_ws;
    float* h        = ws;                     // N*128
    float* h2       = h   + NF * 128;         // N*128
    float* q        = h2  + NF * 128;         // N*128
    float* kk       = q   + NF * 128;         // N*128 (reused as 'gated')
    float* v        = kk  + NF * 128;         // N*128
    float* m        = v   + NF * 128;         // N*64
    float* g8       = m   + NF * 64;          // N*8
    float* agg      = g8  + NF * 8;           // N*128
    float* meanpool = agg + NF * 128;         // N*128
    float* maxpool  = meanpool + NF * 128;    // N*64
    int*   rowptr   = (int*)(maxpool + NF * 64); // N+1
    int*   degi     = rowptr + (NNODES + 1);     // N
    int*   fill     = degi + NNODES;             // N
    int*   csr_src  = fill + NNODES;             // E

    auto gemm = [&](const float* A1, int K1, const float* A2, int K2,
                    const float* B, float* C, int M, int NN, int act) {
        dim3 grid(cdiv(NN, 64), cdiv(M, 64));
        if (act)
            gemm_dual<1><<<grid, 256, 0, stream>>>(A1, K1, A2, K2, B, C, M, NN);
        else
            gemm_dual<0><<<grid, 256, 0, stream>>>(A1, K1, A2, K2, B, C, M, NN);
    };

    // ---- CSR build (edge_index is call-invariant) ----
    hipMemsetAsync(degi, 0, 2 * NNODES * sizeof(int), stream);  // degi + fill
    hist_kernel<<<cdiv(NEDGES, 256), 256, 0, stream>>>(ei, degi);
    scan_kernel<<<1, 1024, 0, stream>>>(degi, rowptr);
    scatter_kernel<<<cdiv(NEDGES, 256), 256, 0, stream>>>(ei, rowptr, fill, csr_src);

    // h = x @ weight_in
    gemm(x, 128, nullptr, 0, w_in, h, NNODES, 128, 0);

    const float* hin = h;
    float* hout = h2;
    for (int L = 0; L < 2; ++L) {
        const float* wq = Wq + (size_t)L * 128 * 128;
        const float* wk = Wk + (size_t)L * 128 * 128;
        const float* wv = Wv + (size_t)L * 128 * 128;
        const float* wm = Wm + (size_t)L * 128 * 64;
        const float* wg = Wg + (size_t)L * 320 * 8;
        const float* wo = Wo + (size_t)L * 256 * 128;

        gemm(hin, 128, nullptr, 0, wq, q,  NNODES, 128, 0);
        gemm(hin, 128, nullptr, 0, wk, kk, NNODES, 128, 0);
        gemm(hin, 128, nullptr, 0, wv, v,  NNODES, 128, 0);
        gemm(hin, 128, nullptr, 0, wm, m,  NNODES, 64,  0);

        fused_edge_kernel<<<cdiv(NNODES, 4), 256, 0, stream>>>(
            rowptr, csr_src, q, kk, v, hin, m, agg, meanpool, maxpool);

        gate_kernel<<<cdiv(NNODES * NHEAD, 256), 256, 0, stream>>>(
            hin, maxpool, meanpool, wg, g8);
        gated_kernel<<<cdiv(NNODES * HIDDIM, 256), 256, 0, stream>>>(g8, agg, kk);

        gemm(hin, 128, kk, 128, wo, hout, NNODES, 128, 1);

        const float* tmp = hout;
        hout = (float*)hin;
        hin = tmp;
    }

    // classifier + log-softmax (hin holds the final hidden state)
    gemm(hin, 128, nullptr, 0, w_out, out, NNODES, NCLS, 0);
    logsoftmax_kernel<<<cdiv(NNODES * 64, 256), 256, 0, stream>>>(out);
}

// Round 4
// 665.656 us; speedup vs baseline: 15.3751x; 1.5578x over previous
//
#include <hip/hip_runtime.h>
#include <math.h>

#define NNODES 50000
#define NEDGES 600000
#define HIDDIM 128
#define NHEAD 8
#define DM 64
#define NCLS 40

typedef __attribute__((ext_vector_type(8))) short short8;
typedef __attribute__((ext_vector_type(4))) float f32x4;

static __device__ __forceinline__ unsigned short f2bf(float f) {
    unsigned u = __float_as_uint(f);
    unsigned r = (u + 0x7fffu + ((u >> 16) & 1u)) >> 16;
    return (unsigned short)r;
}
static __device__ __forceinline__ float bf2f(unsigned short s) {
    return __uint_as_float(((unsigned)s) << 16);
}

// ---------------- bf16 MFMA GEMM (no LDS) ---------------------------------
// C[M,NN] = act( [A1|A2][M,K1+K2] @ B ), B given pre-transposed bf16 BT[NN][K].
// Block = 256 thr = 4 waves; tile BM=256 (64 rows/wave = 4 m-frags), BN=64.
// Frag layouts (16x16x32 bf16): A row=l&15,k=8*(l>>4)+j ; B col=l&15,same k;
// D col=l&15,row=4*(l>>4)+reg  [guide §3/§5, m89/m91/m92 verified].
template <int WF32, int WBF16, int ACT>
__global__ __launch_bounds__(256) void gemm_mfma(
    const unsigned short* __restrict__ A1, int K1,
    const unsigned short* __restrict__ A2, int K2,
    const unsigned short* __restrict__ BT,
    float* __restrict__ C, unsigned short* __restrict__ Cb,
    int M, int NN)
{
    const int K = K1 + K2;
    const int l = threadIdx.x & 63, wv = threadIdx.x >> 6;
    const int r = l & 15, g = l >> 4;
    const int row0 = blockIdx.y * 256 + wv * 64;
    const int col0 = blockIdx.x * 64;

    f32x4 acc[4][4] = {};

    for (int k0 = 0; k0 < K; k0 += 32) {
        const unsigned short* Ak;
        int ka, Kact;
        if (k0 < K1) { Ak = A1; ka = k0; Kact = K1; }
        else         { Ak = A2; ka = k0 - K1; Kact = K2; }

        short8 a[4], b[4];
#pragma unroll
        for (int m = 0; m < 4; ++m) {
            int row = row0 + m * 16 + r;
            if (row < M)
                a[m] = *reinterpret_cast<const short8*>(Ak + (size_t)row * Kact + ka + 8 * g);
            else
                a[m] = short8{0, 0, 0, 0, 0, 0, 0, 0};
        }
#pragma unroll
        for (int n = 0; n < 4; ++n) {
            int col = col0 + n * 16 + r;
            b[n] = *reinterpret_cast<const short8*>(BT + (size_t)col * K + k0 + 8 * g);
        }
#pragma unroll
        for (int m = 0; m < 4; ++m)
#pragma unroll
            for (int n = 0; n < 4; ++n)
                acc[m][n] = __builtin_amdgcn_mfma_f32_16x16x32_bf16(a[m], b[n], acc[m][n], 0, 0, 0);
    }

#pragma unroll
    for (int m = 0; m < 4; ++m) {
#pragma unroll
        for (int j = 0; j < 4; ++j) {
            int row = row0 + m * 16 + 4 * g + j;
            if (row >= M) continue;
#pragma unroll
            for (int n = 0; n < 4; ++n) {
                int col = col0 + n * 16 + r;
                if (col >= NN) continue;
                float vv = acc[m][n][j];
                if (ACT) vv = vv > 0.f ? vv : 0.1f * vv;
                if (WF32)  C[(size_t)row * NN + col] = vv;
                if (WBF16) Cb[(size_t)row * NN + col] = f2bf(vv);
            }
        }
    }
}

// ---------------- weight pack: fp32 [K][NN] -> bf16 BT [NNpad][K] ----------
// BT pool layout (element offsets):
//   BTin    @ 0       : 128x128
//   BTqkvm0 @ 16384   : 448x128   (cols: q|k|v|m)
//   BTqkvm1 @ 73728   : 448x128
//   BTo0    @ 131072  : 128x256
//   BTo1    @ 163840  : 128x256
//   BTout   @ 196608  : 64x128    (cols 40..63 zero-padded)
#define BT_TOTAL 204800
__global__ __launch_bounds__(256) void pack_weights(
    const float* __restrict__ w_in, const float* __restrict__ w_out,
    const float* __restrict__ Wq, const float* __restrict__ Wk,
    const float* __restrict__ Wv, const float* __restrict__ Wm,
    const float* __restrict__ Wo, unsigned short* __restrict__ BT)
{
    int i = blockIdx.x * 256 + threadIdx.x;
    if (i >= BT_TOTAL) return;
    float val;
    if (i < 16384) {
        int c = i >> 7, k = i & 127;
        val = w_in[k * 128 + c];
    } else if (i < 131072) {
        int li = i - 16384;
        int L = li / 57344, t = li % 57344;
        int c = t >> 7, k = t & 127;
        if      (c < 128) val = Wq[L * 16384 + k * 128 + c];
        else if (c < 256) val = Wk[L * 16384 + k * 128 + (c - 128)];
        else if (c < 384) val = Wv[L * 16384 + k * 128 + (c - 256)];
        else              val = Wm[L * 8192  + k * 64  + (c - 384)];
    } else if (i < 196608) {
        int li = i - 131072;
        int L = li / 32768, t = li % 32768;
        int c = t >> 8, k = t & 255;
        val = Wo[L * 32768 + k * 128 + c];
    } else {
        int t = i - 196608;
        int c = t >> 7, k = t & 127;
        val = (c < NCLS) ? w_out[k * NCLS + c] : 0.f;
    }
    BT[i] = f2bf(val);
}

// ---------------- x -> bf16 -----------------------------------------------
__global__ __launch_bounds__(256) void convert_x_kernel(
    const float* __restrict__ x, unsigned int* __restrict__ xb2)
{
    int i = blockIdx.x * 256 + threadIdx.x;          // pairs
    if (i >= NNODES * HIDDIM / 2) return;
    float2 f = *reinterpret_cast<const float2*>(x + (size_t)i * 2);
    xb2[i] = (unsigned)f2bf(f.x) | ((unsigned)f2bf(f.y) << 16);
}

// ---------------- CSR build ------------------------------------------------
__global__ __launch_bounds__(256) void hist_kernel(
    const int* __restrict__ ei, int* __restrict__ degi)
{
    int e = blockIdx.x * 256 + threadIdx.x;
    if (e >= NEDGES) return;
    unsigned d = (unsigned)ei[NEDGES + e]; if (d >= NNODES) d = 0;
    atomicAdd(&degi[d], 1);
}

__global__ __launch_bounds__(1024) void scan_kernel(
    const int* __restrict__ degi, int* __restrict__ rowptr)
{
    __shared__ int sh[1024];
    const int t = threadIdx.x;
    const int chunk = (NNODES + 1023) / 1024;
    int lo = t * chunk, hi = min(lo + chunk, NNODES);
    int s = 0;
    for (int i = lo; i < hi; ++i) s += degi[i];
    sh[t] = s;
    __syncthreads();
    for (int off = 1; off < 1024; off <<= 1) {
        int v = (t >= off) ? sh[t - off] : 0;
        __syncthreads();
        sh[t] += v;
        __syncthreads();
    }
    int excl = (t == 0) ? 0 : sh[t - 1];
    for (int i = lo; i < hi; ++i) {
        rowptr[i] = excl;
        excl += degi[i];
    }
    if (t == 1023) rowptr[NNODES] = excl;
}

__global__ __launch_bounds__(256) void scatter_kernel(
    const int* __restrict__ ei, const int* __restrict__ rowptr,
    int* __restrict__ fill, int* __restrict__ csr_src)
{
    int e = blockIdx.x * 256 + threadIdx.x;
    if (e >= NEDGES) return;
    unsigned s = (unsigned)ei[e];          if (s >= NNODES) s = 0;
    unsigned d = (unsigned)ei[NEDGES + e]; if (d >= NNODES) d = 0;
    int pos = rowptr[d] + atomicAdd(&fill[d], 1);
    csr_src[pos] = (int)s;
}

// ---------------- fused per-node edge phase (bf16 gathers) ----------------
// one wave per dst node; lane l owns cols 2l,2l+1 (head = l>>3).
// qkvm: bf16 [N][448] (q|k|v|m), hb: bf16 [N][128].
__global__ __launch_bounds__(256) void fused_edge_kernel(
    const int* __restrict__ rowptr, const int* __restrict__ csr_src,
    const unsigned short* __restrict__ qkvm, const unsigned short* __restrict__ hb,
    float* __restrict__ agg, float* __restrict__ meanpool,
    float* __restrict__ maxpool)
{
    int node = blockIdx.x * 4 + (threadIdx.x >> 6);
    if (node >= NNODES) return;
    const int lane = threadIdx.x & 63;
    const int c2 = lane * 2;

    const int start = rowptr[node], end = rowptr[node + 1];
    const int deg = end - start;

    unsigned qu = *reinterpret_cast<const unsigned*>(qkvm + (size_t)node * 448 + c2);
    float qx = __uint_as_float(qu << 16);
    float qy = __uint_as_float(qu & 0xffff0000u);

    float mr = -INFINITY, dr = 0.f;
    float a0 = 0.f, a1 = 0.f;
    float ms0 = 0.f, ms1 = 0.f;
    float mm = -INFINITY;

    for (int p = start; p < end; ++p) {
        int s = csr_src[p];
        const unsigned short* srow = qkvm + (size_t)s * 448;
        unsigned ku = *reinterpret_cast<const unsigned*>(srow + 128 + c2);
        unsigned vu = *reinterpret_cast<const unsigned*>(srow + 256 + c2);
        unsigned hu = *reinterpret_cast<const unsigned*>(hb + (size_t)s * 128 + c2);
        float mv = bf2f(srow[384 + lane]);

        float kx = __uint_as_float(ku << 16), ky = __uint_as_float(ku & 0xffff0000u);
        float vx = __uint_as_float(vu << 16), vy = __uint_as_float(vu & 0xffff0000u);
        float hx = __uint_as_float(hu << 16), hy = __uint_as_float(hu & 0xffff0000u);

        float sc = qx * kx + qy * ky;
        sc += __shfl_xor(sc, 1);
        sc += __shfl_xor(sc, 2);
        sc += __shfl_xor(sc, 4);

        if (sc > mr) {
            float scale = __expf(mr - sc);
            dr *= scale; a0 *= scale; a1 *= scale;
            mr = sc;
        }
        float ex = __expf(sc - mr);
        dr += ex;
        a0 = fmaf(ex, vx, a0);
        a1 = fmaf(ex, vy, a1);

        ms0 += hx; ms1 += hy;
        mm = fmaxf(mm, mv);
    }

    float inv  = 1.f / (dr + 1e-16f);
    float invd = 1.f / fmaxf((float)deg, 1.f);
    if (deg == 0) { mm = 0.f; a0 = 0.f; a1 = 0.f; inv = 0.f; }

    float* ag = agg + (size_t)node * HIDDIM + c2;
    ag[0] = a0 * inv; ag[1] = a1 * inv;
    float* mp = meanpool + (size_t)node * HIDDIM + c2;
    mp[0] = ms0 * invd; mp[1] = ms1 * invd;
    maxpool[(size_t)node * DM + lane] = mm;
}

// ---------------- gate / gated / log-softmax ------------------------------
__global__ __launch_bounds__(256) void gate_kernel(
    const float* __restrict__ h, const float* __restrict__ maxpool,
    const float* __restrict__ meanpool, const float* __restrict__ Wg,
    float* __restrict__ g8)
{
    int idx = blockIdx.x * 256 + threadIdx.x;
    if (idx >= NNODES * NHEAD) return;
    int n = idx >> 3, j = idx & 7;
    const float* hr = h + (size_t)n * HIDDIM;
    float sacc = 0.f;
    for (int c = 0; c < HIDDIM; ++c) sacc += hr[c] * Wg[c * NHEAD + j];
    const float* mp = maxpool + (size_t)n * DM;
    for (int c = 0; c < DM; ++c) sacc += mp[c] * Wg[(HIDDIM + c) * NHEAD + j];
    const float* ms = meanpool + (size_t)n * HIDDIM;
    for (int c = 0; c < HIDDIM; ++c) sacc += ms[c] * Wg[(HIDDIM + DM + c) * NHEAD + j];
    g8[idx] = 1.0f / (1.0f + __expf(-sacc));
}

__global__ __launch_bounds__(256) void gated_kernel(
    const float* __restrict__ g8, const float* __restrict__ agg,
    unsigned short* __restrict__ gatedb)
{
    int idx = blockIdx.x * 256 + threadIdx.x;
    if (idx >= NNODES * HIDDIM) return;
    int n = idx >> 7, c = idx & 127;
    gatedb[idx] = f2bf(g8[n * NHEAD + (c >> 4)] * agg[idx]);
}

__global__ __launch_bounds__(256) void logsoftmax_kernel(float* __restrict__ out)
{
    int gt = blockIdx.x * 256 + threadIdx.x;
    int wid = gt >> 6;
    int lane = threadIdx.x & 63;
    if (wid >= NNODES) return;
    float* row = out + (size_t)wid * NCLS;
    float x = (lane < NCLS) ? row[lane] : -INFINITY;
    float mx = x;
#pragma unroll
    for (int off = 32; off; off >>= 1) mx = fmaxf(mx, __shfl_xor(mx, off));
    float ex = (lane < NCLS) ? __expf(x - mx) : 0.f;
    float sm = ex;
#pragma unroll
    for (int off = 32; off; off >>= 1) sm += __shfl_xor(sm, off);
    float lse = mx + logf(sm);
    if (lane < NCLS) row[lane] = x - lse;
}

// ---------------- host ----------------------------------------------------
static inline int cdiv(int a, int b) { return (a + b - 1) / b; }

extern "C" void kernel_launch(void* const* d_in, const int* in_sizes, int n_in,
                              void* d_out, int out_size, void* d_ws, size_t ws_size,
                              hipStream_t stream)
{
    const float* x     = (const float*)d_in[0];
    const int*   ei    = (const int*)d_in[1];
    const float* w_in  = (const float*)d_in[2];
    const float* w_out = (const float*)d_in[3];
    const float* Wq    = (const float*)d_in[4];
    const float* Wk    = (const float*)d_in[5];
    const float* Wv    = (const float*)d_in[6];
    const float* Wm    = (const float*)d_in[7];
    const float* Wg    = (const float*)d_in[8];
    const float* Wo    = (const float*)d_in[9];
    float* out = (float*)d_out;

    const size_t NF = NNODES;
    // fp32 section
    float* h        = (float*)d_ws;            // N*128
    float* h2       = h        + NF * 128;     // N*128
    float* agg      = h2       + NF * 128;     // N*128
    float* meanpool = agg      + NF * 128;     // N*128
    float* maxpool  = meanpool + NF * 128;     // N*64
    float* g8       = maxpool  + NF * 64;      // N*8
    // bf16 section
    unsigned short* xb     = (unsigned short*)(g8 + NF * 8);  // N*128
    unsigned short* hb0    = xb     + NF * 128;               // N*128
    unsigned short* hb1    = hb0    + NF * 128;               // N*128
    unsigned short* qkvm   = hb1    + NF * 128;               // N*448
    unsigned short* gatedb = qkvm   + NF * 448;               // N*128
    unsigned short* BTpool = gatedb + NF * 128;               // 204800
    // int section
    int* rowptr  = (int*)(BTpool + BT_TOTAL);                 // N+1
    int* degi    = rowptr + (NNODES + 1);                     // N
    int* fill    = degi + NNODES;                             // N
    int* csr_src = fill + NNODES;                             // E

    const unsigned short* BTin    = BTpool;
    const unsigned short* BTqkvm0 = BTpool + 16384;
    const unsigned short* BTqkvm1 = BTpool + 73728;
    const unsigned short* BTo0    = BTpool + 131072;
    const unsigned short* BTo1    = BTpool + 163840;
    const unsigned short* BTout   = BTpool + 196608;

    // ---- prep: weight pack, x conversion, CSR build ----
    pack_weights<<<cdiv(BT_TOTAL, 256), 256, 0, stream>>>(
        w_in, w_out, Wq, Wk, Wv, Wm, Wo, BTpool);
    convert_x_kernel<<<cdiv(NNODES * HIDDIM / 2, 256), 256, 0, stream>>>(
        x, (unsigned int*)xb);
    hipMemsetAsync(degi, 0, 2 * NNODES * sizeof(int), stream);
    hist_kernel<<<cdiv(NEDGES, 256), 256, 0, stream>>>(ei, degi);
    scan_kernel<<<1, 1024, 0, stream>>>(degi, rowptr);
    scatter_kernel<<<cdiv(NEDGES, 256), 256, 0, stream>>>(ei, rowptr, fill, csr_src);

    const dim3 g128(2, cdiv(NNODES, 256));
    const dim3 g448(7, cdiv(NNODES, 256));
    const dim3 g40 (1, cdiv(NNODES, 256));

    // h = x @ w_in  (fp32 h for gates + bf16 hb for GEMMs/gathers)
    gemm_mfma<1, 1, 0><<<g128, 256, 0, stream>>>(
        xb, 128, nullptr, 0, BTin, h, hb0, NNODES, 128);

    const float* hin = h;  float* hout = h2;
    const unsigned short* hbin = hb0;  unsigned short* hbout = hb1;
    for (int L = 0; L < 2; ++L) {
        const unsigned short* btq = L ? BTqkvm1 : BTqkvm0;
        const unsigned short* bto = L ? BTo1 : BTo0;
        const float* wg = Wg + (size_t)L * 320 * 8;

        // qkvm = h @ [wq|wk|wv|wm]  (bf16 out only)
        gemm_mfma<0, 1, 0><<<g448, 256, 0, stream>>>(
            hbin, 128, nullptr, 0, btq, nullptr, qkvm, NNODES, 448);

        fused_edge_kernel<<<cdiv(NNODES, 4), 256, 0, stream>>>(
            rowptr, csr_src, qkvm, hbin, agg, meanpool, maxpool);

        gate_kernel<<<cdiv(NNODES * NHEAD, 256), 256, 0, stream>>>(
            hin, maxpool, meanpool, wg, g8);
        gated_kernel<<<cdiv(NNODES * HIDDIM, 256), 256, 0, stream>>>(
            g8, agg, gatedb);

        // h' = leaky_relu([h | gated] @ wo)  (fp32 + bf16)
        gemm_mfma<1, 1, 1><<<g128, 256, 0, stream>>>(
            hbin, 128, gatedb, 128, bto, hout, hbout, NNODES, 128);

        const float* t1 = hout; hout = (float*)hin; hin = t1;
        unsigned short* t2 = hbout; hbout = (unsigned short*)hbin; hbin = t2;
    }

    // classifier + log-softmax
    gemm_mfma<1, 0, 0><<<g40, 256, 0, stream>>>(
        hbin, 128, nullptr, 0, BTout, out, nullptr, NNODES, NCLS);
    logsoftmax_kernel<<<cdiv(NNODES * 64, 256), 256, 0, stream>>>(out);
}

// Round 6
// 551.810 us; speedup vs baseline: 18.5472x; 1.2063x over previous
//
#include <hip/hip_runtime.h>
#include <math.h>

#define NNODES 50000
#define NEDGES 600000
#define HIDDIM 128
#define NHEAD 8
#define DM 64
#define NCLS 40
#define FSTR 576   // packed feature row: [q 128 | k 128 | v 128 | m 64 | h 128]

typedef __attribute__((ext_vector_type(8))) short short8;
typedef __attribute__((ext_vector_type(4))) float f32x4;

static __device__ __forceinline__ unsigned short f2bf(float f) {
    unsigned u = __float_as_uint(f);
    unsigned r = (u + 0x7fffu + ((u >> 16) & 1u)) >> 16;
    return (unsigned short)r;
}
static __device__ __forceinline__ float bflo(unsigned u) { return __uint_as_float(u << 16); }
static __device__ __forceinline__ float bfhi(unsigned u) { return __uint_as_float(u & 0xffff0000u); }
static __device__ __forceinline__ float bf2f(unsigned short s) {
    return __uint_as_float(((unsigned)s) << 16);
}

// ---------------- bf16 MFMA GEMM (no LDS) ---------------------------------
// C = act( [A1|A2] @ B ), B pre-transposed bf16 BT[NN][K1+K2].
// Block = 4 waves; BM=256 (64 rows/wave), BN=64.
// Frags (16x16x32 bf16): A row=l&15,k=8*(l>>4)+j ; D col=l&15,row=4*(l>>4)+reg.
template <int WF32, int WB1, int ACT>
__global__ __launch_bounds__(256) void gemm_mfma(
    const unsigned short* __restrict__ A1, int lda1, int K1,
    const unsigned short* __restrict__ A2, int lda2, int K2,
    const unsigned short* __restrict__ BT,
    float* __restrict__ C, int ldc,
    unsigned short* __restrict__ Cb1, int ldb1, int off1,
    int M, int NN)
{
    const int K = K1 + K2;
    const int l = threadIdx.x & 63, wv = threadIdx.x >> 6;
    const int r = l & 15, g = l >> 4;
    const int row0 = blockIdx.y * 256 + wv * 64;
    const int col0 = blockIdx.x * 64;

    f32x4 acc[4][4] = {};

    for (int k0 = 0; k0 < K; k0 += 32) {
        const unsigned short* Ak;
        int ka, lda;
        if (k0 < K1) { Ak = A1; ka = k0; lda = lda1; }
        else         { Ak = A2; ka = k0 - K1; lda = lda2; }

        short8 a[4], b[4];
#pragma unroll
        for (int m = 0; m < 4; ++m) {
            int row = row0 + m * 16 + r;
            if (row < M)
                a[m] = *reinterpret_cast<const short8*>(Ak + (size_t)row * lda + ka + 8 * g);
            else
                a[m] = short8{0, 0, 0, 0, 0, 0, 0, 0};
        }
#pragma unroll
        for (int n = 0; n < 4; ++n) {
            int col = col0 + n * 16 + r;
            b[n] = *reinterpret_cast<const short8*>(BT + (size_t)col * K + k0 + 8 * g);
        }
#pragma unroll
        for (int m = 0; m < 4; ++m)
#pragma unroll
            for (int n = 0; n < 4; ++n)
                acc[m][n] = __builtin_amdgcn_mfma_f32_16x16x32_bf16(a[m], b[n], acc[m][n], 0, 0, 0);
    }

#pragma unroll
    for (int m = 0; m < 4; ++m) {
#pragma unroll
        for (int j = 0; j < 4; ++j) {
            int row = row0 + m * 16 + 4 * g + j;
            if (row >= M) continue;
#pragma unroll
            for (int n = 0; n < 4; ++n) {
                int col = col0 + n * 16 + r;
                if (col >= NN) continue;
                float vv = acc[m][n][j];
                if (ACT) vv = vv > 0.f ? vv : 0.1f * vv;
                if (WF32) C[(size_t)row * ldc + col] = vv;
                if (WB1)  Cb1[(size_t)row * ldb1 + off1 + col] = f2bf(vv);
            }
        }
    }
}

// ---------------- weight pack: fp32 [K][NN] -> bf16 BT [NNpad][K] ----------
//   BTin    @ 0       : 128x128
//   BTqkvm0 @ 16384   : 448x128   (cols: q|k|v|m)
//   BTqkvm1 @ 73728   : 448x128
//   BTo0    @ 131072  : 128x256
//   BTo1    @ 163840  : 128x256
//   BTout   @ 196608  : 64x128    (cols 40..63 zero-padded)
#define BT_TOTAL 204800
__global__ __launch_bounds__(256) void pack_weights(
    const float* __restrict__ w_in, const float* __restrict__ w_out,
    const float* __restrict__ Wq, const float* __restrict__ Wk,
    const float* __restrict__ Wv, const float* __restrict__ Wm,
    const float* __restrict__ Wo, unsigned short* __restrict__ BT)
{
    int i = blockIdx.x * 256 + threadIdx.x;
    if (i >= BT_TOTAL) return;
    float val;
    if (i < 16384) {
        int c = i >> 7, k = i & 127;
        val = w_in[k * 128 + c];
    } else if (i < 131072) {
        int li = i - 16384;
        int L = li / 57344, t = li % 57344;
        int c = t >> 7, k = t & 127;
        if      (c < 128) val = Wq[L * 16384 + k * 128 + c];
        else if (c < 256) val = Wk[L * 16384 + k * 128 + (c - 128)];
        else if (c < 384) val = Wv[L * 16384 + k * 128 + (c - 256)];
        else              val = Wm[L * 8192  + k * 64  + (c - 384)];
    } else if (i < 196608) {
        int li = i - 131072;
        int L = li / 32768, t = li % 32768;
        int c = t >> 8, k = t & 255;
        val = Wo[L * 32768 + k * 128 + c];
    } else {
        int t = i - 196608;
        int c = t >> 7, k = t & 127;
        val = (c < NCLS) ? w_out[k * NCLS + c] : 0.f;
    }
    BT[i] = f2bf(val);
}

// ---------------- x -> bf16 -----------------------------------------------
__global__ __launch_bounds__(256) void convert_x_kernel(
    const float* __restrict__ x, unsigned int* __restrict__ xb2)
{
    int i = blockIdx.x * 256 + threadIdx.x;          // pairs
    if (i >= NNODES * HIDDIM / 2) return;
    float2 f = *reinterpret_cast<const float2*>(x + (size_t)i * 2);
    xb2[i] = (unsigned)f2bf(f.x) | ((unsigned)f2bf(f.y) << 16);
}

// ---------------- CSR build ------------------------------------------------
__global__ __launch_bounds__(256) void hist_kernel(
    const int* __restrict__ ei, int* __restrict__ degi)
{
    int e = blockIdx.x * 256 + threadIdx.x;
    if (e >= NEDGES) return;
    unsigned d = (unsigned)ei[NEDGES + e]; if (d >= NNODES) d = 0;
    atomicAdd(&degi[d], 1);
}

__global__ __launch_bounds__(1024) void scan_kernel(
    const int* __restrict__ degi, int* __restrict__ rowptr)
{
    __shared__ int sh[1024];
    const int t = threadIdx.x;
    const int chunk = (NNODES + 1023) / 1024;
    int lo = t * chunk, hi = min(lo + chunk, NNODES);
    int s = 0;
    for (int i = lo; i < hi; ++i) s += degi[i];
    sh[t] = s;
    __syncthreads();
    for (int off = 1; off < 1024; off <<= 1) {
        int v = (t >= off) ? sh[t - off] : 0;
        __syncthreads();
        sh[t] += v;
        __syncthreads();
    }
    int excl = (t == 0) ? 0 : sh[t - 1];
    for (int i = lo; i < hi; ++i) {
        rowptr[i] = excl;
        excl += degi[i];
    }
    if (t == 1023) rowptr[NNODES] = excl;
}

__global__ __launch_bounds__(256) void scatter_kernel(
    const int* __restrict__ ei, const int* __restrict__ rowptr,
    int* __restrict__ fill, int* __restrict__ csr_src)
{
    int e = blockIdx.x * 256 + threadIdx.x;
    if (e >= NEDGES) return;
    unsigned s = (unsigned)ei[e];          if (s >= NNODES) s = 0;
    unsigned d = (unsigned)ei[NEDGES + e]; if (d >= NNODES) d = 0;
    int pos = rowptr[d] + atomicAdd(&fill[d], 1);
    csr_src[pos] = (int)s;
}

// ---------------- fused edge phase + gate + gated --------------------------
// one wave per dst node; lane l owns cols 2l,2l+1 (head = l>>3).
// feat: bf16 [N][576] = [q|k|v|m|h]. Writes ONLY gatedb [N][128] bf16.
__global__ __launch_bounds__(256) void fused_edge_kernel(
    const int* __restrict__ rowptr, const int* __restrict__ csr_src,
    const unsigned short* __restrict__ feat, const float* __restrict__ Wg,
    unsigned short* __restrict__ gatedb)
{
    int node = blockIdx.x * 4 + (threadIdx.x >> 6);
    if (node >= NNODES) return;
    const int lane = threadIdx.x & 63;
    const int c2 = lane * 2;

    const int start = rowptr[node], end = rowptr[node + 1];
    const int deg = end - start;

    const unsigned short* frow = feat + (size_t)node * FSTR;
    unsigned qu = *reinterpret_cast<const unsigned*>(frow + c2);
    float qx = bflo(qu), qy = bfhi(qu);

    float mr = -INFINITY, dr = 0.f;
    float a0 = 0.f, a1 = 0.f;
    float ms0 = 0.f, ms1 = 0.f;
    float mm = -INFINITY;

    int p = start;
    for (; p + 2 <= end; p += 2) {
        int s0 = csr_src[p], s1 = csr_src[p + 1];
        const unsigned short* r0 = feat + (size_t)s0 * FSTR;
        const unsigned short* r1 = feat + (size_t)s1 * FSTR;
        unsigned ku0 = *reinterpret_cast<const unsigned*>(r0 + 128 + c2);
        unsigned vu0 = *reinterpret_cast<const unsigned*>(r0 + 256 + c2);
        float    mv0 = bf2f(r0[384 + lane]);
        unsigned hu0 = *reinterpret_cast<const unsigned*>(r0 + 448 + c2);
        unsigned ku1 = *reinterpret_cast<const unsigned*>(r1 + 128 + c2);
        unsigned vu1 = *reinterpret_cast<const unsigned*>(r1 + 256 + c2);
        float    mv1 = bf2f(r1[384 + lane]);
        unsigned hu1 = *reinterpret_cast<const unsigned*>(r1 + 448 + c2);

        float sc0 = qx * bflo(ku0) + qy * bfhi(ku0);
        float sc1 = qx * bflo(ku1) + qy * bfhi(ku1);
        sc0 += __shfl_xor(sc0, 1);  sc1 += __shfl_xor(sc1, 1);
        sc0 += __shfl_xor(sc0, 2);  sc1 += __shfl_xor(sc1, 2);
        sc0 += __shfl_xor(sc0, 4);  sc1 += __shfl_xor(sc1, 4);

        float nm = fmaxf(mr, fmaxf(sc0, sc1));
        float scale = __expf(mr - nm);            // mr=-inf -> 0, harmless
        float e0 = __expf(sc0 - nm), e1 = __expf(sc1 - nm);
        dr = dr * scale + e0 + e1;
        a0 = a0 * scale; a0 = fmaf(e0, bflo(vu0), a0); a0 = fmaf(e1, bflo(vu1), a0);
        a1 = a1 * scale; a1 = fmaf(e0, bfhi(vu0), a1); a1 = fmaf(e1, bfhi(vu1), a1);
        mr = nm;

        ms0 += bflo(hu0) + bflo(hu1);
        ms1 += bfhi(hu0) + bfhi(hu1);
        mm = fmaxf(mm, fmaxf(mv0, mv1));
    }
    if (p < end) {
        int s0 = csr_src[p];
        const unsigned short* r0 = feat + (size_t)s0 * FSTR;
        unsigned ku0 = *reinterpret_cast<const unsigned*>(r0 + 128 + c2);
        unsigned vu0 = *reinterpret_cast<const unsigned*>(r0 + 256 + c2);
        float    mv0 = bf2f(r0[384 + lane]);
        unsigned hu0 = *reinterpret_cast<const unsigned*>(r0 + 448 + c2);

        float sc0 = qx * bflo(ku0) + qy * bfhi(ku0);
        sc0 += __shfl_xor(sc0, 1);
        sc0 += __shfl_xor(sc0, 2);
        sc0 += __shfl_xor(sc0, 4);

        float nm = fmaxf(mr, sc0);
        float scale = __expf(mr - nm);
        float e0 = __expf(sc0 - nm);
        dr = dr * scale + e0;
        a0 = fmaf(e0, bflo(vu0), a0 * scale);
        a1 = fmaf(e0, bfhi(vu0), a1 * scale);
        mr = nm;

        ms0 += bflo(hu0);
        ms1 += bfhi(hu0);
        mm = fmaxf(mm, mv0);
    }

    float inv  = 1.f / (dr + 1e-16f);
    float invd = 1.f / fmaxf((float)deg, 1.f);
    if (deg == 0) { mm = 0.f; inv = 0.f; }
    float msx = ms0 * invd, msy = ms1 * invd;

    // ---- gate: g = sigmoid([h_i, maxpool, meanpool] @ Wg), fused in-wave --
    unsigned hou = *reinterpret_cast<const unsigned*>(frow + 448 + c2);
    float hx = bflo(hou), hy = bfhi(hou);

    const float* w0 = Wg + (size_t)c2 * 8;            // row 2l
    const float* w1 = Wg + (size_t)(c2 + 1) * 8;      // row 2l+1
    const float* w2 = Wg + (size_t)(128 + lane) * 8;  // maxpool row l
    const float* w3 = Wg + (size_t)(192 + c2) * 8;    // meanpool row 2l
    const float* w4 = Wg + (size_t)(193 + c2) * 8;    // meanpool row 2l+1

    float part[8];
#pragma unroll
    for (int j = 0; j < 8; ++j)
        part[j] = hx * w0[j] + hy * w1[j] + mm * w2[j] + msx * w3[j] + msy * w4[j];
#pragma unroll
    for (int off = 1; off < 64; off <<= 1)
#pragma unroll
        for (int j = 0; j < 8; ++j)
            part[j] += __shfl_xor(part[j], off);

    float g = 1.f / (1.f + __expf(-part[lane >> 3]));
    float o0 = g * a0 * inv, o1 = g * a1 * inv;
    unsigned outu = (unsigned)f2bf(o0) | ((unsigned)f2bf(o1) << 16);
    *reinterpret_cast<unsigned*>(gatedb + (size_t)node * HIDDIM + c2) = outu;
}

// ---------------- log-softmax ----------------------------------------------
__global__ __launch_bounds__(256) void logsoftmax_kernel(float* __restrict__ out)
{
    int gt = blockIdx.x * 256 + threadIdx.x;
    int wid = gt >> 6;
    int lane = threadIdx.x & 63;
    if (wid >= NNODES) return;
    float* row = out + (size_t)wid * NCLS;
    float x = (lane < NCLS) ? row[lane] : -INFINITY;
    float mx = x;
#pragma unroll
    for (int off = 32; off; off >>= 1) mx = fmaxf(mx, __shfl_xor(mx, off));
    float ex = (lane < NCLS) ? __expf(x - mx) : 0.f;
    float sm = ex;
#pragma unroll
    for (int off = 32; off; off >>= 1) sm += __shfl_xor(sm, off);
    float lse = mx + logf(sm);
    if (lane < NCLS) row[lane] = x - lse;
}

// ---------------- host ----------------------------------------------------
static inline int cdiv(int a, int b) { return (a + b - 1) / b; }

extern "C" void kernel_launch(void* const* d_in, const int* in_sizes, int n_in,
                              void* d_out, int out_size, void* d_ws, size_t ws_size,
                              hipStream_t stream)
{
    const float* x     = (const float*)d_in[0];
    const int*   ei    = (const int*)d_in[1];
    const float* w_in  = (const float*)d_in[2];
    const float* w_out = (const float*)d_in[3];
    const float* Wq    = (const float*)d_in[4];
    const float* Wk    = (const float*)d_in[5];
    const float* Wv    = (const float*)d_in[6];
    const float* Wm    = (const float*)d_in[7];
    const float* Wg    = (const float*)d_in[8];
    const float* Wo    = (const float*)d_in[9];
    float* out = (float*)d_out;

    const size_t NF = NNODES;
    unsigned short* xb     = (unsigned short*)d_ws;           // N*128
    unsigned short* feat0  = xb    + NF * 128;                // N*576
    unsigned short* feat1  = feat0 + NF * FSTR;               // N*576
    unsigned short* gatedb = feat1 + NF * FSTR;               // N*128
    unsigned short* BTpool = gatedb + NF * 128;               // 204800
    int* rowptr  = (int*)(BTpool + BT_TOTAL);                 // N+1
    int* degi    = rowptr + (NNODES + 1);                     // N
    int* fill    = degi + NNODES;                             // N
    int* csr_src = fill + NNODES;                             // E

    const unsigned short* BTin    = BTpool;
    const unsigned short* BTqkvm0 = BTpool + 16384;
    const unsigned short* BTqkvm1 = BTpool + 73728;
    const unsigned short* BTo0    = BTpool + 131072;
    const unsigned short* BTo1    = BTpool + 163840;
    const unsigned short* BTout   = BTpool + 196608;

    // ---- prep ----
    pack_weights<<<cdiv(BT_TOTAL, 256), 256, 0, stream>>>(
        w_in, w_out, Wq, Wk, Wv, Wm, Wo, BTpool);
    convert_x_kernel<<<cdiv(NNODES * HIDDIM / 2, 256), 256, 0, stream>>>(
        x, (unsigned int*)xb);
    hipMemsetAsync(degi, 0, 2 * NNODES * sizeof(int), stream);
    hist_kernel<<<cdiv(NEDGES, 256), 256, 0, stream>>>(ei, degi);
    scan_kernel<<<1, 1024, 0, stream>>>(degi, rowptr);
    scatter_kernel<<<cdiv(NEDGES, 256), 256, 0, stream>>>(ei, rowptr, fill, csr_src);

    const dim3 g128(2, cdiv(NNODES, 256));
    const dim3 g448(7, cdiv(NNODES, 256));
    const dim3 g40 (1, cdiv(NNODES, 256));

    // h0 = x @ w_in  -> feat0[.,448..575]
    gemm_mfma<0, 1, 0><<<g128, 256, 0, stream>>>(
        xb, 128, 128, nullptr, 0, 0, BTin,
        nullptr, 0, feat0, FSTR, 448, NNODES, 128);

    unsigned short* featA = feat0;
    unsigned short* featB = feat1;
    for (int L = 0; L < 2; ++L) {
        const unsigned short* btq = L ? BTqkvm1 : BTqkvm0;
        const unsigned short* bto = L ? BTo1 : BTo0;
        const float* wg = Wg + (size_t)L * 320 * 8;

        // [q|k|v|m] = h @ [wq|wk|wv|wm]  -> feat[.,0..447]
        gemm_mfma<0, 1, 0><<<g448, 256, 0, stream>>>(
            featA + 448, FSTR, 128, nullptr, 0, 0, btq,
            nullptr, 0, featA, FSTR, 0, NNODES, 448);

        fused_edge_kernel<<<cdiv(NNODES, 4), 256, 0, stream>>>(
            rowptr, csr_src, featA, wg, gatedb);

        // h' = leaky_relu([h | gated] @ wo) -> featB[.,448..575]
        gemm_mfma<0, 1, 1><<<g128, 256, 0, stream>>>(
            featA + 448, FSTR, 128, gatedb, 128, 128, bto,
            nullptr, 0, featB, FSTR, 448, NNODES, 128);

        unsigned short* t = featA; featA = featB; featB = t;
    }

    // classifier + log-softmax (featA holds final hidden state)
    gemm_mfma<1, 0, 0><<<g40, 256, 0, stream>>>(
        featA + 448, FSTR, 128, nullptr, 0, 0, BTout,
        out, NCLS, nullptr, 0, 0, NNODES, NCLS);
    logsoftmax_kernel<<<cdiv(NNODES * 64, 256), 256, 0, stream>>>(out);
}